// Round 10
// baseline (299.926 us; speedup 1.0000x reference)
//
#include <hip/hip_runtime.h>
#include <hip/hip_bf16.h>

#define BB 4
#define H_ 128
#define W_ 128
#define HWP 16384
#define KOFF 18

typedef short short8 __attribute__((ext_vector_type(8)));
typedef float floatx4 __attribute__((ext_vector_type(4)));

// ---- workspace layout (float offsets) ----
#define WS_AB   16
#define WS_CVT  288
#define CVT_TOTAL 4447396
#define WS_WF1  4447744
#define WS_WF2  4484608
#define WS_XT   4558336
#define WS_Y1   7835136
#define WS_Y1T  16223744
#define WS_XTL  18320896         // aliases 2nd half of Y1T; XTL dead before bn_apply_dual writes Y1T
#define WS_WFO1 20418048         // offset-conv wf frags stage1 (hi+lo, 4 ct): 18432 floats
#define WS_WFO2 20436480         // offset-conv wf frags stage2 (hi+lo, 4 ct): 36864 floats
#define WS_PART 21600000
#define WS_Y2   WS_Y1            // Y1 (fp32 NCHW) dead after stage-1 BN-apply; alias
// Y1T_lo lives at WS_CVT (X slot; X fp32 dead after xt_build)

// cvt-relative input offsets
#define R_X     0
#define R_WOFF1 4194304
#define R_BOFF1 4204672
#define R_W1    4204690
#define R_B1    4278418
#define R_G1    4278546
#define R_BE1   4278674
#define R_WOFF2 4278802
#define R_BOFF2 4299538
#define R_W2    4299556
#define R_B2    4447012
#define R_G2    4447140
#define R_BE2   4447268

struct SrcPtrs { const void* p[13]; };

__device__ inline short f2bf(float f) {
    __hip_bfloat16 h = __float2bfloat16(f);
    return *reinterpret_cast<short*>(&h);
}
__device__ inline float bf2f(unsigned short u) {
    return __uint_as_float(((unsigned int)u) << 16);
}
__device__ inline float bfu_lo(unsigned int u) { return __uint_as_float(u << 16); }
__device__ inline float bfu_hi(unsigned int u) { return __uint_as_float(u & 0xFFFF0000u); }
__device__ inline float rl_f(float v, int i) {
    return __int_as_float(__builtin_amdgcn_readlane(__float_as_int(v), i));
}

__global__ void probe_dtype_k(const unsigned int* __restrict__ g1, int* __restrict__ flag) {
    if (threadIdx.x == 0 && blockIdx.x == 0) {
        flag[0] = ((g1[0] & 0xFFFFu) != 0u) ? 1 : 0;
    }
}

__global__ __launch_bounds__(256) void convert_inputs_k(SrcPtrs sp, float* __restrict__ dst,
                                                        const int* __restrict__ flag, int total) {
    int i = blockIdx.x * 256 + threadIdx.x;
    if (i >= total) return;
    constexpr int prefix[13] = {0, R_WOFF1, R_BOFF1, R_W1, R_B1, R_G1, R_BE1,
                                R_WOFF2, R_BOFF2, R_W2, R_B2, R_G2, R_BE2};
    const void* src = sp.p[0];
    int base = 0;
#pragma unroll
    for (int q = 1; q < 13; ++q) {
        if (i >= prefix[q]) { src = sp.p[q]; base = prefix[q]; }
    }
    int local = i - base;
    float v;
    if (flag[0] != 0) {
        v = bf2f(((const unsigned short*)src)[local]);
    } else {
        v = ((const float*)src)[local];
    }
    dst[i] = v;
}

// Pack main conv weights into MFMA A-fragment order; frag-k = kk*CIN + ci
template <int CIN>
__global__ __launch_bounds__(256) void wf_build_k(const float* __restrict__ w, short* __restrict__ wf) {
    constexpr int KSTEPS = CIN * 9 / 32;
    int idx = blockIdx.x * 256 + threadIdx.x;
    int j    = idx & 7;
    int lane = (idx >> 3) & 63;
    int rem  = idx >> 9;
    int ks   = rem % KSTEPS;
    int ct   = rem / KSTEPS;
    int co = ct * 16 + (lane & 15);
    int k  = ks * 32 + (lane >> 4) * 8 + j;
    int ci = k & (CIN - 1);
    int kk = k / CIN;
    wf[idx] = f2bf(w[(co * CIN + ci) * 9 + kk]);
}

// Pack offset-conv weights (CO=18 padded to 32), 4 ct-tiles: cc=0,1 hi; cc=2,3 lo residual.
template <int CIN>
__global__ __launch_bounds__(256) void wf_off_build_k(const float* __restrict__ w, short* __restrict__ wf) {
    constexpr int KSTEPS = CIN * 9 / 32;
    int idx = blockIdx.x * 256 + threadIdx.x;   // total 4*KSTEPS*512
    int j    = idx & 7;
    int lane = (idx >> 3) & 63;
    int rem  = idx >> 9;
    int ks   = rem % KSTEPS;
    int cc   = rem / KSTEPS;          // 0..3
    int sel  = cc >> 1;
    int co = (cc & 1) * 16 + (lane & 15);
    int k  = ks * 32 + (lane >> 4) * 8 + j;
    int ci = k & (CIN - 1);
    int kk = k / CIN;
    float v = (co < KOFF) ? w[(co * CIN + ci) * 9 + kk] : 0.f;
    short hi = f2bf(v);
    wf[idx] = sel ? f2bf(v - bf2f((unsigned short)hi)) : hi;
}

// X (fp32 NCHW, C=64) -> XT (bf16 NHWC hi) + XTL (bf16 NHWC lo residual)
__global__ __launch_bounds__(256) void xt_build_k(const float* __restrict__ x,
                                                  unsigned short* __restrict__ xt,
                                                  unsigned short* __restrict__ xtl) {
    __shared__ __align__(4) short s_t[64 * 66];
    __shared__ __align__(4) short s_tl[64 * 66];
    int bi  = blockIdx.x;           // 4 * 256
    int hw0 = (bi & 255) * 64;
    int b   = bi >> 8;
    int t   = threadIdx.x;
    int hwp = t & 63;
#pragma unroll
    for (int it = 0; it < 16; ++it) {
        int c = it * 4 + (t >> 6);
        float v = x[((long)(b * 64 + c) << 14) + hw0 + hwp];
        short hi = f2bf(v);
        s_t[hwp * 66 + c]  = hi;
        s_tl[hwp * 66 + c] = f2bf(v - bf2f((unsigned short)hi));
    }
    __syncthreads();
#pragma unroll
    for (int it = 0; it < 8; ++it) {
        int i  = it * 256 + t;
        int c2 = (i & 31) * 2;
        int hw2 = i >> 5;
        long da = ((long)((b << 14) + hw0 + hw2)) * 64 + c2;
        *(int*)&xt[da]  = *(const int*)&s_t[hw2 * 66 + c2];
        *(int*)&xtl[da] = *(const int*)&s_tl[hw2 * 66 + c2];
    }
}

// ---- im2col table for offset conv (no offsets; tap grid only) ----
__device__ inline int conv_tpk(int h, int w0, int lane, int wv) {
    int tpk = 0;
    if (lane < 36) {
        int r = wv + 8 * lane;
        int p = r & 31;
        int k = r >> 5;
        int y = h - 1 + k / 3;
        int x = w0 + p - 1 + (k % 3);
        int valid = (y >= 0 && y < H_ && x >= 0 && x < W_) ? 1 : 0;
        int yc = min(max(y, 0), H_ - 1), xc = min(max(x, 0), W_ - 1);
        tpk = (yc * W_ + xc) | (valid << 16);
    }
    return tpk;
}

// ---- T14 split conv gathers: load (global->regs, masked) and store (regs->LDS) ----
template <int NJ>
__device__ inline void conv_load64(const unsigned short* __restrict__ xb, unsigned int* ub,
                                   int half, int li, int tpk, int J0) {
#pragma unroll
    for (int j = 0; j < NJ; ++j) {
        int jj = J0 + j;
        int pkA = __builtin_amdgcn_readlane(tpk, 2 * jj);
        int pkB = __builtin_amdgcn_readlane(tpk, 2 * jj + 1);
        int pk = half ? pkB : pkA;
        unsigned int u = *(const unsigned int*)(xb + (pk & 0xFFFF) * 64 + 2 * li);
        ub[j] = (pk >> 16) ? u : 0u;
    }
}
template <int NJ, int PADc, int KKB>
__device__ inline void conv_store64(short* __restrict__ s_samp, const unsigned int* ub,
                                    int half, int li, int wv, int J0) {
#pragma unroll
    for (int j = 0; j < NJ; ++j) {
        int jj = J0 + j;
        int r = wv + 8 * (half ? (2 * jj + 1) : (2 * jj));
        *(unsigned int*)&s_samp[(r & 31) * PADc + ((r >> 5) - KKB) * 64 + 2 * li] = ub[j];
    }
}
template <int I0, int NJ>
__device__ inline void conv_load128(const unsigned short* __restrict__ xb, unsigned int* ub,
                                    int lane, int tpk) {
#pragma unroll
    for (int j = 0; j < NJ; ++j) {
        int pk = __builtin_amdgcn_readlane(tpk, I0 + j);
        unsigned int u = *(const unsigned int*)(xb + (pk & 0xFFFF) * 128 + 2 * lane);
        ub[j] = (pk >> 16) ? u : 0u;
    }
}
template <int I0, int NJ, int KKB, int PADc>
__device__ inline void conv_store128(short* __restrict__ s_samp, const unsigned int* ub,
                                     int wv, int lane) {
#pragma unroll
    for (int j = 0; j < NJ; ++j) {
        int r = wv + 8 * (I0 + j);
        *(unsigned int*)&s_samp[(r & 31) * PADc + ((r >> 5) - KKB) * 128 + 2 * lane] = ub[j];
    }
}

// ---- deform table build from LDS offsets (lane i owns row r = wv + 8*i, i < 36) ----
__device__ inline void build_table2_lds(const float* __restrict__ s_off,
                                        int h, int w0, int lane, int wv,
                                        int& tpk, float& tw0, float& tw1, float& tw2, float& tw3) {
    tpk = 0; tw0 = tw1 = tw2 = tw3 = 0.f;
    if (lane < 36) {
        int r = wv + 8 * lane;
        int p = r & 31;
        int k = r >> 5;
        int wpix = w0 + p;
        float oy = s_off[(2 * k) * 32 + p];
        float ox = s_off[(2 * k + 1) * 32 + p];
        float py = (float)(h - 1 + (k / 3)) + oy;
        float px = (float)(wpix - 1 + (k % 3)) + ox;
        float fy = floorf(py), fx = floorf(px);
        float wy = py - fy, wx = px - fx;
        int y0 = (int)fy, x0 = (int)fx;
        int y1 = y0 + 1, x1 = x0 + 1;
        bool vy0 = (y0 >= 0) && (y0 < H_);
        bool vy1 = (y1 >= 0) && (y1 < H_);
        bool vx0 = (x0 >= 0) && (x0 < W_);
        bool vx1 = (x1 >= 0) && (x1 < W_);
        float wy0 = 1.f - wy, wx0 = 1.f - wx;
        tw0 = (vy0 && vx0) ? wy0 * wx0 : 0.f;
        tw1 = (vy0 && vx1) ? wy0 * wx  : 0.f;
        tw2 = (vy1 && vx0) ? wy  * wx0 : 0.f;
        tw3 = (vy1 && vx1) ? wy  * wx  : 0.f;
        int iy0 = min(max(y0, 0), H_ - 1), iy1 = min(max(y1, 0), H_ - 1);
        int ix0 = min(max(x0, 0), W_ - 1), ix1 = min(max(x1, 0), W_ - 1);
        int dx = ix1 - ix0;
        int dy = iy1 - iy0;
        tpk = (iy0 * W_ + ix0) | (dx << 14) | (dy << 15);
    }
}

// Batched bilinear gather, CIN=128 (row r = wv + 8*i, pixel = r&31, tap = r>>5)
template <int NB>
__device__ inline void gather_batch128v2(const unsigned short* __restrict__ xb, short* __restrict__ s_samp,
                                         int i0, int kkbase, int wv, int lane,
                                         int tpk, float tw0, float tw1, float tw2, float tw3) {
    constexpr int PADc = 520;
    uint4 ub[NB];
#pragma unroll
    for (int j = 0; j < NB; ++j) {
        int pk = __builtin_amdgcn_readlane(tpk, i0 + j);
        const unsigned short* b00 = xb + (pk & 0x3FFF) * 128;
        const unsigned short* b01 = b00 + ((pk >> 14) & 1) * 128;
        const unsigned short* b10 = b00 + ((pk >> 15) & 1) * (W_ * 128);
        const unsigned short* b11 = b01 + ((pk >> 15) & 1) * (W_ * 128);
        ub[j].x = *(const unsigned int*)(b00 + 2 * lane);
        ub[j].y = *(const unsigned int*)(b01 + 2 * lane);
        ub[j].z = *(const unsigned int*)(b10 + 2 * lane);
        ub[j].w = *(const unsigned int*)(b11 + 2 * lane);
    }
#pragma unroll
    for (int j = 0; j < NB; ++j) {
        int i = i0 + j;
        int r = wv + 8 * i;
        float w00 = rl_f(tw0, i), w01 = rl_f(tw1, i), w10 = rl_f(tw2, i), w11 = rl_f(tw3, i);
        float vlo = w00 * bfu_lo(ub[j].x) + w01 * bfu_lo(ub[j].y)
                  + w10 * bfu_lo(ub[j].z) + w11 * bfu_lo(ub[j].w);
        float vhi = w00 * bfu_hi(ub[j].x) + w01 * bfu_hi(ub[j].y)
                  + w10 * bfu_hi(ub[j].z) + w11 * bfu_hi(ub[j].w);
        __hip_bfloat162 h2 = __float22bfloat162_rn(make_float2(vlo, vhi));
        *(unsigned int*)&s_samp[(r & 31) * PADc + ((r >> 5) - kkbase) * 128 + 2 * lane] =
            *reinterpret_cast<unsigned int*>(&h2);
    }
}

// Batched bilinear gather, CIN=64, dual-row: lanes 0-31 row iA, lanes 32-63 row iB
template <int NBP>
__device__ inline void gather_batch64v2(const unsigned short* __restrict__ xb, short* __restrict__ s_samp,
                                        int i0, int kkbase, int wv, int half, int li,
                                        int tpk, float tw0, float tw1, float tw2, float tw3) {
    constexpr int PADc = 520;
    uint4 ub[NBP];
#pragma unroll
    for (int j = 0; j < NBP; ++j) {
        int iA = i0 + 2 * j, iB = iA + 1;
        int pkA = __builtin_amdgcn_readlane(tpk, iA);
        int pkB = __builtin_amdgcn_readlane(tpk, iB);
        int pk = half ? pkB : pkA;
        const unsigned short* b00 = xb + (pk & 0x3FFF) * 64;
        const unsigned short* b01 = b00 + ((pk >> 14) & 1) * 64;
        const unsigned short* b10 = b00 + ((pk >> 15) & 1) * (W_ * 64);
        const unsigned short* b11 = b01 + ((pk >> 15) & 1) * (W_ * 64);
        ub[j].x = *(const unsigned int*)(b00 + 2 * li);
        ub[j].y = *(const unsigned int*)(b01 + 2 * li);
        ub[j].z = *(const unsigned int*)(b10 + 2 * li);
        ub[j].w = *(const unsigned int*)(b11 + 2 * li);
    }
#pragma unroll
    for (int j = 0; j < NBP; ++j) {
        int iA = i0 + 2 * j, iB = iA + 1;
        float w00 = half ? rl_f(tw0, iB) : rl_f(tw0, iA);
        float w01 = half ? rl_f(tw1, iB) : rl_f(tw1, iA);
        float w10 = half ? rl_f(tw2, iB) : rl_f(tw2, iA);
        float w11 = half ? rl_f(tw3, iB) : rl_f(tw3, iA);
        float vlo = w00 * bfu_lo(ub[j].x) + w01 * bfu_lo(ub[j].y)
                  + w10 * bfu_lo(ub[j].z) + w11 * bfu_lo(ub[j].w);
        float vhi = w00 * bfu_hi(ub[j].x) + w01 * bfu_hi(ub[j].y)
                  + w10 * bfu_hi(ub[j].z) + w11 * bfu_hi(ub[j].w);
        __hip_bfloat162 h2 = __float22bfloat162_rn(make_float2(vlo, vhi));
        int r = wv + 8 * (half ? iB : iA);
        *(unsigned int*)&s_samp[(r & 31) * PADc + ((r >> 5) - kkbase) * 64 + 2 * li] =
            *reinterpret_cast<unsigned int*>(&h2);
    }
}

// ===================================================================================
// FUSED stage kernel, CIN=64. v3 wave-roles + 8+1 tap chunks at PADc 520.
// LDS: s_samp 33.3K + s_off 2.25K = 35.6K -> 4 blocks/CU (full 32-wave cap)
// ===================================================================================
__global__ __launch_bounds__(512, 4) void fused64_k(const unsigned short* __restrict__ xt,
                                                    const unsigned short* __restrict__ xtl,
                                                    const short* __restrict__ wfo,
                                                    const float* __restrict__ boff,
                                                    const short* __restrict__ wf,
                                                    const float* __restrict__ bias,
                                                    float* __restrict__ out) {
    constexpr int KSTEPS = 18;
    constexpr int PADc = 520;
    __shared__ __align__(16) short s_samp[32 * PADc];
    __shared__ float s_off[KOFF * 32];
    float* s_redf = (float*)s_samp;       // 12.3 KB scratch, valid only in reduction window

    int bi = blockIdx.x;
    int w0 = (bi & 3) * 32;
    int h  = (bi >> 2) & 127;
    int b  = bi >> 9;
    int t  = threadIdx.x;
    int lane = t & 63;
    int wv   = t >> 6;

    const unsigned short* xbh = xt  + (long)b * HWP * 64;
    const unsigned short* xbl = xtl + (long)b * HWP * 64;
    int half = lane >> 5, li = lane & 31;
    int p_   = lane & 15;
    int quad = lane >> 4;

    // ---------------- offset conv phase (split-bf16, dual-ptile, ksl4, 8+1 chunks) ----------------
    {
        int tpkc = conv_tpk(h, w0, lane, wv);
        int ct  = wv & 1;
        int ksl = wv >> 1;          // 0..3
        floatx4 acc0, acc1;
#pragma unroll
        for (int r = 0; r < 4; ++r) {
            int co = ct * 16 + quad * 4 + r;
            float bv = (ksl == 0 && co < KOFF) ? boff[co] : 0.f;
            acc0[r] = bv;
            acc1[r] = bv;
        }

        // A-hi: taps 0-7 (ks 0..15)
        {
            unsigned int ubA[16];
            conv_load64<16>(xbh, ubA, half, li, tpkc, 0);
            conv_store64<16, PADc, 0>(s_samp, ubA, half, li, wv, 0);
        }
        __syncthreads();
        unsigned int ubC[2];
        conv_load64<2>(xbh, ubC, half, li, tpkc, 16);     // C-hi loads hidden under A-hi MFMAs
#pragma unroll
        for (int ki = 0; ki < 4; ++ki) {
            int ks = ksl * 4 + ki;
            short8 b0 = *(const short8*)&s_samp[p_ * PADc + ks * 32 + quad * 8];
            short8 b1 = *(const short8*)&s_samp[(16 + p_) * PADc + ks * 32 + quad * 8];
            short8 ah = *(const short8*)&wfo[(((long)ct * KSTEPS + ks) * 64 + lane) * 8];
            short8 al = *(const short8*)&wfo[(((long)(2 + ct) * KSTEPS + ks) * 64 + lane) * 8];
            acc0 = __builtin_amdgcn_mfma_f32_16x16x32_bf16(ah, b0, acc0, 0, 0, 0);
            acc0 = __builtin_amdgcn_mfma_f32_16x16x32_bf16(al, b0, acc0, 0, 0, 0);
            acc1 = __builtin_amdgcn_mfma_f32_16x16x32_bf16(ah, b1, acc1, 0, 0, 0);
            acc1 = __builtin_amdgcn_mfma_f32_16x16x32_bf16(al, b1, acc1, 0, 0, 0);
        }
        __syncthreads();
        conv_store64<2, PADc, 8>(s_samp, ubC, half, li, wv, 16);   // C at tap-8 -> slot 0
        __syncthreads();
        unsigned int ubA2[16];
        conv_load64<16>(xbl, ubA2, half, li, tpkc, 0);    // A-lo loads hidden under C-hi MFMAs
        if (ksl < 2) {
            int ks = 16 + ksl;
            short8 b0 = *(const short8*)&s_samp[p_ * PADc + (ks - 16) * 32 + quad * 8];
            short8 b1 = *(const short8*)&s_samp[(16 + p_) * PADc + (ks - 16) * 32 + quad * 8];
            short8 ah = *(const short8*)&wfo[(((long)ct * KSTEPS + ks) * 64 + lane) * 8];
            short8 al = *(const short8*)&wfo[(((long)(2 + ct) * KSTEPS + ks) * 64 + lane) * 8];
            acc0 = __builtin_amdgcn_mfma_f32_16x16x32_bf16(ah, b0, acc0, 0, 0, 0);
            acc0 = __builtin_amdgcn_mfma_f32_16x16x32_bf16(al, b0, acc0, 0, 0, 0);
            acc1 = __builtin_amdgcn_mfma_f32_16x16x32_bf16(ah, b1, acc1, 0, 0, 0);
            acc1 = __builtin_amdgcn_mfma_f32_16x16x32_bf16(al, b1, acc1, 0, 0, 0);
        }
        __syncthreads();
        conv_store64<16, PADc, 0>(s_samp, ubA2, half, li, wv, 0);
        __syncthreads();
        conv_load64<2>(xbl, ubC, half, li, tpkc, 16);     // C-lo loads hidden under A-lo MFMAs
#pragma unroll
        for (int ki = 0; ki < 4; ++ki) {
            int ks = ksl * 4 + ki;
            short8 b0 = *(const short8*)&s_samp[p_ * PADc + ks * 32 + quad * 8];
            short8 b1 = *(const short8*)&s_samp[(16 + p_) * PADc + ks * 32 + quad * 8];
            short8 ah = *(const short8*)&wfo[(((long)ct * KSTEPS + ks) * 64 + lane) * 8];
            acc0 = __builtin_amdgcn_mfma_f32_16x16x32_bf16(ah, b0, acc0, 0, 0, 0);
            acc1 = __builtin_amdgcn_mfma_f32_16x16x32_bf16(ah, b1, acc1, 0, 0, 0);
        }
        __syncthreads();
        conv_store64<2, PADc, 8>(s_samp, ubC, half, li, wv, 16);
        __syncthreads();
        if (ksl < 2) {
            int ks = 16 + ksl;
            short8 b0 = *(const short8*)&s_samp[p_ * PADc + (ks - 16) * 32 + quad * 8];
            short8 b1 = *(const short8*)&s_samp[(16 + p_) * PADc + (ks - 16) * 32 + quad * 8];
            short8 ah = *(const short8*)&wfo[(((long)ct * KSTEPS + ks) * 64 + lane) * 8];
            acc0 = __builtin_amdgcn_mfma_f32_16x16x32_bf16(ah, b0, acc0, 0, 0, 0);
            acc1 = __builtin_amdgcn_mfma_f32_16x16x32_bf16(ah, b1, acc1, 0, 0, 0);
        }

        // K-reduction through s_samp scratch
        __syncthreads();
        if (ksl != 0) {
#pragma unroll
            for (int r = 0; r < 4; ++r) {
                s_redf[(((ksl - 1) * 4 + ct * 2 + 0) * 256) + (quad * 4 + r) * 16 + p_] = acc0[r];
                s_redf[(((ksl - 1) * 4 + ct * 2 + 1) * 256) + (quad * 4 + r) * 16 + p_] = acc1[r];
            }
        }
        __syncthreads();
        if (ksl == 0) {
#pragma unroll
            for (int r = 0; r < 4; ++r) {
                int co = ct * 16 + quad * 4 + r;
                if (co < KOFF) {
                    float v0 = acc0[r], v1 = acc1[r];
#pragma unroll
                    for (int s = 1; s < 4; ++s) {
                        v0 += s_redf[(((s - 1) * 4 + ct * 2 + 0) * 256) + (quad * 4 + r) * 16 + p_];
                        v1 += s_redf[(((s - 1) * 4 + ct * 2 + 1) * 256) + (quad * 4 + r) * 16 + p_];
                    }
                    s_off[co * 32 + p_]      = v0;
                    s_off[co * 32 + 16 + p_] = v1;
                }
            }
        }
        __syncthreads();
    }

    // ---------------- deform conv phase (8+1 tap chunks) ----------------
    int tpk; float tw0, tw1, tw2, tw3;
    build_table2_lds(s_off, h, w0, lane, wv, tpk, tw0, tw1, tw2, tw3);

    int ct = wv;
    floatx4 acc0, acc1;
#pragma unroll
    for (int r = 0; r < 4; ++r) {
        float bv = bias[ct * 16 + quad * 4 + r];
        acc0[r] = bv;
        acc1[r] = bv;
    }

    gather_batch64v2<8>(xbh, s_samp,  0, 0, wv, half, li, tpk, tw0, tw1, tw2, tw3);
    gather_batch64v2<8>(xbh, s_samp, 16, 0, wv, half, li, tpk, tw0, tw1, tw2, tw3);
    __syncthreads();
#pragma unroll 4
    for (int ks = 0; ks < 16; ++ks) {
        short8 a  = *(const short8*)&wf[(((long)ct * KSTEPS + ks) * 64 + lane) * 8];
        short8 b0 = *(const short8*)&s_samp[p_ * PADc + ks * 32 + quad * 8];
        short8 b1 = *(const short8*)&s_samp[(16 + p_) * PADc + ks * 32 + quad * 8];
        acc0 = __builtin_amdgcn_mfma_f32_16x16x32_bf16(a, b0, acc0, 0, 0, 0);
        acc1 = __builtin_amdgcn_mfma_f32_16x16x32_bf16(a, b1, acc1, 0, 0, 0);
    }
    __syncthreads();

    gather_batch64v2<2>(xbh, s_samp, 32, 8, wv, half, li, tpk, tw0, tw1, tw2, tw3);
    __syncthreads();
#pragma unroll
    for (int ks = 16; ks < KSTEPS; ++ks) {
        short8 a  = *(const short8*)&wf[(((long)ct * KSTEPS + ks) * 64 + lane) * 8];
        short8 b0 = *(const short8*)&s_samp[p_ * PADc + (ks - 16) * 32 + quad * 8];
        short8 b1 = *(const short8*)&s_samp[(16 + p_) * PADc + (ks - 16) * 32 + quad * 8];
        acc0 = __builtin_amdgcn_mfma_f32_16x16x32_bf16(a, b0, acc0, 0, 0, 0);
        acc1 = __builtin_amdgcn_mfma_f32_16x16x32_bf16(a, b1, acc1, 0, 0, 0);
    }

    long ob = ((long)(b * 128) << 14) + (h << 7) + w0 + p_;
#pragma unroll
    for (int r = 0; r < 4; ++r) {
        long cpl = (long)(ct * 16 + quad * 4 + r) << 14;
        out[ob + cpl]      = acc0[r];
        out[ob + 16 + cpl] = acc1[r];
    }
}

// ===================================================================================
// FUSED stage kernel, CIN=128. v3 wave-roles + 4+4+1 tap chunks at PADc 520.
// LDS: s_samp 33.3K + s_off 2.25K = 35.6K -> 4 blocks/CU
// ===================================================================================
__global__ __launch_bounds__(512, 4) void fused128_k(const unsigned short* __restrict__ xt,
                                                     const unsigned short* __restrict__ xtl,
                                                     const short* __restrict__ wfo,
                                                     const float* __restrict__ boff,
                                                     const short* __restrict__ wf,
                                                     const float* __restrict__ bias,
                                                     float* __restrict__ out) {
    constexpr int KSTEPS = 36;
    constexpr int PADc = 520;
    __shared__ __align__(16) short s_samp[32 * PADc];
    __shared__ float s_off[KOFF * 32];
    float* s_redf = (float*)s_samp;

    int bi = blockIdx.x;
    int w0 = (bi & 3) * 32;
    int h  = (bi >> 2) & 127;
    int b  = bi >> 9;
    int t  = threadIdx.x;
    int lane = t & 63;
    int wv   = t >> 6;

    const unsigned short* xbh = xt  + (long)b * HWP * 128;
    const unsigned short* xbl = xtl + (long)b * HWP * 128;
    int p_   = lane & 15;
    int quad = lane >> 4;

    // ---------------- offset conv phase (split-bf16, dual-ptile, ksl4, 4+4+1 chunks) ----------------
    {
        int tpkc = conv_tpk(h, w0, lane, wv);
        int ct  = wv & 1;
        int ksl = wv >> 1;          // 0..3
        floatx4 acc0, acc1;
#pragma unroll
        for (int r = 0; r < 4; ++r) {
            int co = ct * 16 + quad * 4 + r;
            float bv = (ksl == 0 && co < KOFF) ? boff[co] : 0.f;
            acc0[r] = bv;
            acc1[r] = bv;
        }

        unsigned int ubA[16], ubB[16], ubC[4];
        // A-hi: taps 0..3 (ks 0..15)
        conv_load128<0, 16>(xbh, ubA, lane, tpkc);
        conv_store128<0, 16, 0, PADc>(s_samp, ubA, wv, lane);
        __syncthreads();
        conv_load128<16, 16>(xbh, ubB, lane, tpkc);   // B-hi loads hidden under A-hi MFMAs
#pragma unroll
        for (int ki = 0; ki < 4; ++ki) {
            int ks = ksl * 4 + ki;
            short8 b0 = *(const short8*)&s_samp[p_ * PADc + ks * 32 + quad * 8];
            short8 b1 = *(const short8*)&s_samp[(16 + p_) * PADc + ks * 32 + quad * 8];
            short8 ah = *(const short8*)&wfo[(((long)ct * KSTEPS + ks) * 64 + lane) * 8];
            short8 al = *(const short8*)&wfo[(((long)(2 + ct) * KSTEPS + ks) * 64 + lane) * 8];
            acc0 = __builtin_amdgcn_mfma_f32_16x16x32_bf16(ah, b0, acc0, 0, 0, 0);
            acc0 = __builtin_amdgcn_mfma_f32_16x16x32_bf16(al, b0, acc0, 0, 0, 0);
            acc1 = __builtin_amdgcn_mfma_f32_16x16x32_bf16(ah, b1, acc1, 0, 0, 0);
            acc1 = __builtin_amdgcn_mfma_f32_16x16x32_bf16(al, b1, acc1, 0, 0, 0);
        }
        __syncthreads();
        conv_store128<16, 16, 4, PADc>(s_samp, ubB, wv, lane);
        __syncthreads();
        conv_load128<32, 4>(xbh, ubC, lane, tpkc);    // C-hi loads hidden under B-hi MFMAs
#pragma unroll
        for (int ki = 0; ki < 4; ++ki) {
            int ks = 16 + ksl * 4 + ki;
            short8 b0 = *(const short8*)&s_samp[p_ * PADc + (ks - 16) * 32 + quad * 8];
            short8 b1 = *(const short8*)&s_samp[(16 + p_) * PADc + (ks - 16) * 32 + quad * 8];
            short8 ah = *(const short8*)&wfo[(((long)ct * KSTEPS + ks) * 64 + lane) * 8];
            short8 al = *(const short8*)&wfo[(((long)(2 + ct) * KSTEPS + ks) * 64 + lane) * 8];
            acc0 = __builtin_amdgcn_mfma_f32_16x16x32_bf16(ah, b0, acc0, 0, 0, 0);
            acc0 = __builtin_amdgcn_mfma_f32_16x16x32_bf16(al, b0, acc0, 0, 0, 0);
            acc1 = __builtin_amdgcn_mfma_f32_16x16x32_bf16(ah, b1, acc1, 0, 0, 0);
            acc1 = __builtin_amdgcn_mfma_f32_16x16x32_bf16(al, b1, acc1, 0, 0, 0);
        }
        __syncthreads();
        conv_store128<32, 4, 8, PADc>(s_samp, ubC, wv, lane);
        __syncthreads();
        conv_load128<0, 16>(xbl, ubA, lane, tpkc);    // A-lo loads hidden under C-hi MFMAs
        {
            int ks = 32 + ksl;
            short8 b0 = *(const short8*)&s_samp[p_ * PADc + (ks - 32) * 32 + quad * 8];
            short8 b1 = *(const short8*)&s_samp[(16 + p_) * PADc + (ks - 32) * 32 + quad * 8];
            short8 ah = *(const short8*)&wfo[(((long)ct * KSTEPS + ks) * 64 + lane) * 8];
            short8 al = *(const short8*)&wfo[(((long)(2 + ct) * KSTEPS + ks) * 64 + lane) * 8];
            acc0 = __builtin_amdgcn_mfma_f32_16x16x32_bf16(ah, b0, acc0, 0, 0, 0);
            acc0 = __builtin_amdgcn_mfma_f32_16x16x32_bf16(al, b0, acc0, 0, 0, 0);
            acc1 = __builtin_amdgcn_mfma_f32_16x16x32_bf16(ah, b1, acc1, 0, 0, 0);
            acc1 = __builtin_amdgcn_mfma_f32_16x16x32_bf16(al, b1, acc1, 0, 0, 0);
        }
        __syncthreads();
        conv_store128<0, 16, 0, PADc>(s_samp, ubA, wv, lane);
        __syncthreads();
        conv_load128<16, 16>(xbl, ubB, lane, tpkc);   // B-lo loads hidden under A-lo MFMAs
#pragma unroll
        for (int ki = 0; ki < 4; ++ki) {
            int ks = ksl * 4 + ki;
            short8 b0 = *(const short8*)&s_samp[p_ * PADc + ks * 32 + quad * 8];
            short8 b1 = *(const short8*)&s_samp[(16 + p_) * PADc + ks * 32 + quad * 8];
            short8 ah = *(const short8*)&wfo[(((long)ct * KSTEPS + ks) * 64 + lane) * 8];
            acc0 = __builtin_amdgcn_mfma_f32_16x16x32_bf16(ah, b0, acc0, 0, 0, 0);
            acc1 = __builtin_amdgcn_mfma_f32_16x16x32_bf16(ah, b1, acc1, 0, 0, 0);
        }
        __syncthreads();
        conv_store128<16, 16, 4, PADc>(s_samp, ubB, wv, lane);
        __syncthreads();
        conv_load128<32, 4>(xbl, ubC, lane, tpkc);    // C-lo loads hidden under B-lo MFMAs
#pragma unroll
        for (int ki = 0; ki < 4; ++ki) {
            int ks = 16 + ksl * 4 + ki;
            short8 b0 = *(const short8*)&s_samp[p_ * PADc + (ks - 16) * 32 + quad * 8];
            short8 b1 = *(const short8*)&s_samp[(16 + p_) * PADc + (ks - 16) * 32 + quad * 8];
            short8 ah = *(const short8*)&wfo[(((long)ct * KSTEPS + ks) * 64 + lane) * 8];
            acc0 = __builtin_amdgcn_mfma_f32_16x16x32_bf16(ah, b0, acc0, 0, 0, 0);
            acc1 = __builtin_amdgcn_mfma_f32_16x16x32_bf16(ah, b1, acc1, 0, 0, 0);
        }
        __syncthreads();
        conv_store128<32, 4, 8, PADc>(s_samp, ubC, wv, lane);
        __syncthreads();
        {
            int ks = 32 + ksl;
            short8 b0 = *(const short8*)&s_samp[p_ * PADc + (ks - 32) * 32 + quad * 8];
            short8 b1 = *(const short8*)&s_samp[(16 + p_) * PADc + (ks - 32) * 32 + quad * 8];
            short8 ah = *(const short8*)&wfo[(((long)ct * KSTEPS + ks) * 64 + lane) * 8];
            acc0 = __builtin_amdgcn_mfma_f32_16x16x32_bf16(ah, b0, acc0, 0, 0, 0);
            acc1 = __builtin_amdgcn_mfma_f32_16x16x32_bf16(ah, b1, acc1, 0, 0, 0);
        }

        // K-reduction through s_samp scratch
        __syncthreads();
        if (ksl != 0) {
#pragma unroll
            for (int r = 0; r < 4; ++r) {
                s_redf[(((ksl - 1) * 4 + ct * 2 + 0) * 256) + (quad * 4 + r) * 16 + p_] = acc0[r];
                s_redf[(((ksl - 1) * 4 + ct * 2 + 1) * 256) + (quad * 4 + r) * 16 + p_] = acc1[r];
            }
        }
        __syncthreads();
        if (ksl == 0) {
#pragma unroll
            for (int r = 0; r < 4; ++r) {
                int co = ct * 16 + quad * 4 + r;
                if (co < KOFF) {
                    float v0 = acc0[r], v1 = acc1[r];
#pragma unroll
                    for (int s = 1; s < 4; ++s) {
                        v0 += s_redf[(((s - 1) * 4 + ct * 2 + 0) * 256) + (quad * 4 + r) * 16 + p_];
                        v1 += s_redf[(((s - 1) * 4 + ct * 2 + 1) * 256) + (quad * 4 + r) * 16 + p_];
                    }
                    s_off[co * 32 + p_]      = v0;
                    s_off[co * 32 + 16 + p_] = v1;
                }
            }
        }
        __syncthreads();
    }

    // ---------------- deform conv phase (4+4+1 tap chunks) ----------------
    int tpk; float tw0, tw1, tw2, tw3;
    build_table2_lds(s_off, h, w0, lane, wv, tpk, tw0, tw1, tw2, tw3);

    int ct = wv;
    floatx4 acc0, acc1;
#pragma unroll
    for (int r = 0; r < 4; ++r) {
        float bv = bias[ct * 16 + quad * 4 + r];
        acc0[r] = bv;
        acc1[r] = bv;
    }

    gather_batch128v2<8>(xbh, s_samp, 0, 0, wv, lane, tpk, tw0, tw1, tw2, tw3);
    gather_batch128v2<8>(xbh, s_samp, 8, 0, wv, lane, tpk, tw0, tw1, tw2, tw3);
    __syncthreads();
#pragma unroll 4
    for (int ks = 0; ks < 16; ++ks) {
        short8 a  = *(const short8*)&wf[(((long)ct * KSTEPS + ks) * 64 + lane) * 8];
        short8 b0 = *(const short8*)&s_samp[p_ * PADc + ks * 32 + quad * 8];
        short8 b1 = *(const short8*)&s_samp[(16 + p_) * PADc + ks * 32 + quad * 8];
        acc0 = __builtin_amdgcn_mfma_f32_16x16x32_bf16(a, b0, acc0, 0, 0, 0);
        acc1 = __builtin_amdgcn_mfma_f32_16x16x32_bf16(a, b1, acc1, 0, 0, 0);
    }
    __syncthreads();

    gather_batch128v2<8>(xbh, s_samp, 16, 4, wv, lane, tpk, tw0, tw1, tw2, tw3);
    gather_batch128v2<8>(xbh, s_samp, 24, 4, wv, lane, tpk, tw0, tw1, tw2, tw3);
    __syncthreads();
#pragma unroll 4
    for (int ks = 16; ks < 32; ++ks) {
        short8 a  = *(const short8*)&wf[(((long)ct * KSTEPS + ks) * 64 + lane) * 8];
        short8 b0 = *(const short8*)&s_samp[p_ * PADc + (ks - 16) * 32 + quad * 8];
        short8 b1 = *(const short8*)&s_samp[(16 + p_) * PADc + (ks - 16) * 32 + quad * 8];
        acc0 = __builtin_amdgcn_mfma_f32_16x16x32_bf16(a, b0, acc0, 0, 0, 0);
        acc1 = __builtin_amdgcn_mfma_f32_16x16x32_bf16(a, b1, acc1, 0, 0, 0);
    }
    __syncthreads();

    gather_batch128v2<4>(xbh, s_samp, 32, 8, wv, lane, tpk, tw0, tw1, tw2, tw3);
    __syncthreads();
#pragma unroll
    for (int ks = 32; ks < KSTEPS; ++ks) {
        short8 a  = *(const short8*)&wf[(((long)ct * KSTEPS + ks) * 64 + lane) * 8];
        short8 b0 = *(const short8*)&s_samp[p_ * PADc + (ks - 32) * 32 + quad * 8];
        short8 b1 = *(const short8*)&s_samp[(16 + p_) * PADc + (ks - 32) * 32 + quad * 8];
        acc0 = __builtin_amdgcn_mfma_f32_16x16x32_bf16(a, b0, acc0, 0, 0, 0);
        acc1 = __builtin_amdgcn_mfma_f32_16x16x32_bf16(a, b1, acc1, 0, 0, 0);
    }

    long ob = ((long)(b * 128) << 14) + (h << 7) + w0 + p_;
#pragma unroll
    for (int r = 0; r < 4; ++r) {
        long cpl = (long)(ct * 16 + quad * 4 + r) << 14;
        out[ob + cpl]      = acc0[r];
        out[ob + 16 + cpl] = acc1[r];
    }
}

// BN stats partials: 512 blocks, one (c,b) plane each
__global__ __launch_bounds__(256) void bn_stats_part_k(const float* __restrict__ y, float* __restrict__ part) {
    int bi = blockIdx.x;
    int c = bi & 127;
    int b = bi >> 7;
    int t = threadIdx.x;
    const float4* p4 = (const float4*)(y + ((long)(b * 128 + c) << 14));
    float sum = 0.f, ss = 0.f;
#pragma unroll
    for (int i = 0; i < 16; ++i) {
        float4 v = p4[t + 256 * i];
        sum += v.x + v.y + v.z + v.w;
        ss  += v.x * v.x + v.y * v.y + v.z * v.z + v.w * v.w;
    }
#pragma unroll
    for (int o = 32; o > 0; o >>= 1) { sum += __shfl_down(sum, o); ss += __shfl_down(ss, o); }
    __shared__ float s1[4], s2[4];
    int wave = t >> 6;
    if ((t & 63) == 0) { s1[wave] = sum; s2[wave] = ss; }
    __syncthreads();
    if (t == 0) {
        part[bi]       = s1[0] + s1[1] + s1[2] + s1[3];
        part[512 + bi] = s2[0] + s2[1] + s2[2] + s2[3];
    }
}

// BN+ReLU: read raw fp32 NCHW, write transposed bf16 NHWC hi + lo copies (no fp32 writeback).
__global__ __launch_bounds__(256) void bn_apply_dual_k(const float* __restrict__ y, const float* __restrict__ part,
                                                       const float* __restrict__ g, const float* __restrict__ be,
                                                       unsigned short* __restrict__ yt,
                                                       unsigned short* __restrict__ ytl) {
    __shared__ __align__(4) short s_t[64 * 134];
    __shared__ __align__(4) short s_tl[64 * 134];
    __shared__ float s_a[128], s_sh[128];
    int t = threadIdx.x;
    if (t < 128) {
        float sum = part[t] + part[128 + t] + part[256 + t] + part[384 + t];
        float ss  = part[512 + t] + part[640 + t] + part[768 + t] + part[896 + t];
        float mean = sum * (1.f / 65536.f);
        float var  = ss  * (1.f / 65536.f) - mean * mean;
        float inv  = rsqrtf(var + 1e-5f);
        float a = g[t] * inv;
        s_a[t]  = a;
        s_sh[t] = be[t] - mean * a;
    }
    __syncthreads();

    int bi  = blockIdx.x;          // 4 * 256
    int hw0 = (bi & 255) * 64;
    int b   = bi >> 8;
    int hwp = t & 63;
#pragma unroll 4
    for (int it = 0; it < 32; ++it) {
        int c = it * 4 + (t >> 6);
        float a = s_a[c], sh = s_sh[c];
        long addr = ((long)(b * 128 + c) << 14) + hw0 + hwp;
        float v = y[addr];
        v = fmaxf(v * a + sh, 0.f);
        short hi = f2bf(v);
        s_t[hwp * 134 + c]  = hi;
        s_tl[hwp * 134 + c] = f2bf(v - bf2f((unsigned short)hi));
    }
    __syncthreads();
#pragma unroll 4
    for (int it = 0; it < 16; ++it) {
        int i   = it * 256 + t;
        int c2  = (i & 63) * 2;
        int hw2 = i >> 6;
        long da = ((long)((b << 14) + hw0 + hw2)) * 128 + c2;
        *(int*)&yt[da]  = *(const int*)&s_t[hw2 * 134 + c2];
        *(int*)&ytl[da] = *(const int*)&s_tl[hw2 * 134 + c2];
    }
}

// Final BN+ReLU -> d_out (fp32 or bf16 per flag).
__global__ __launch_bounds__(256) void bn_apply_out_k(const float* __restrict__ y, const float* __restrict__ part,
                                                      const float* __restrict__ g, const float* __restrict__ be,
                                                      const int* __restrict__ flag, void* __restrict__ out, int total4) {
    __shared__ float s_a[128], s_sh[128];
    int t = threadIdx.x;
    if (t < 128) {
        float sum = part[t] + part[128 + t] + part[256 + t] + part[384 + t];
        float ss  = part[512 + t] + part[640 + t] + part[768 + t] + part[896 + t];
        float mean = sum * (1.f / 65536.f);
        float var  = ss  * (1.f / 65536.f) - mean * mean;
        float inv  = rsqrtf(var + 1e-5f);
        float a = g[t] * inv;
        s_a[t]  = a;
        s_sh[t] = be[t] - mean * a;
    }
    __syncthreads();

    int i = blockIdx.x * 256 + t;
    if (i >= total4) return;
    int c = (i >> 12) & 127;
    float a = s_a[c], sh = s_sh[c];
    float4 v = reinterpret_cast<const float4*>(y)[i];
    v.x = fmaxf(v.x * a + sh, 0.f);
    v.y = fmaxf(v.y * a + sh, 0.f);
    v.z = fmaxf(v.z * a + sh, 0.f);
    v.w = fmaxf(v.w * a + sh, 0.f);
    if (flag[0] != 0) {
        ushort4 u;
        u.x = (unsigned short)f2bf(v.x);
        u.y = (unsigned short)f2bf(v.y);
        u.z = (unsigned short)f2bf(v.z);
        u.w = (unsigned short)f2bf(v.w);
        reinterpret_cast<ushort4*>(out)[i] = u;
    } else {
        reinterpret_cast<float4*>(out)[i] = v;
    }
}

extern "C" void kernel_launch(void* const* d_in, const int* in_sizes, int n_in,
                              void* d_out, int out_size, void* d_ws, size_t ws_size,
                              hipStream_t stream) {
    float* ws   = (float*)d_ws;
    int*   flag = (int*)d_ws;
    float* cvt  = ws + WS_CVT;

    const float* X     = cvt + R_X;
    const float* Woff1 = cvt + R_WOFF1;
    const float* Boff1 = cvt + R_BOFF1;
    const float* W1f   = cvt + R_W1;
    const float* B1f   = cvt + R_B1;
    const float* G1    = cvt + R_G1;
    const float* Be1   = cvt + R_BE1;
    const float* Woff2 = cvt + R_WOFF2;
    const float* Boff2 = cvt + R_BOFF2;
    const float* W2f   = cvt + R_W2;
    const float* B2f   = cvt + R_B2;
    const float* G2    = cvt + R_G2;
    const float* Be2   = cvt + R_BE2;

    short* WF1  = (short*)(ws + WS_WF1);
    short* WF2  = (short*)(ws + WS_WF2);
    short* WFO1 = (short*)(ws + WS_WFO1);
    short* WFO2 = (short*)(ws + WS_WFO2);
    unsigned short* XT   = (unsigned short*)(ws + WS_XT);
    unsigned short* XTL  = (unsigned short*)(ws + WS_XTL);
    unsigned short* Y1T  = (unsigned short*)(ws + WS_Y1T);
    unsigned short* Y1TL = (unsigned short*)(ws + WS_CVT);   // X slot; X fp32 dead after xt_build
    float* PART = ws + WS_PART;
    float* Y1   = ws + WS_Y1;
    float* Y2   = ws + WS_Y2;

    SrcPtrs sp;
    for (int j = 0; j < 13; ++j) sp.p[j] = d_in[j];

    probe_dtype_k<<<1, 64, 0, stream>>>((const unsigned int*)d_in[5], flag);
    convert_inputs_k<<<(CVT_TOTAL + 255) / 256, 256, 0, stream>>>(sp, cvt, flag, CVT_TOTAL);
    wf_build_k<64><<<288, 256, 0, stream>>>(W1f, WF1);
    wf_build_k<128><<<576, 256, 0, stream>>>(W2f, WF2);
    wf_off_build_k<64><<<144, 256, 0, stream>>>(Woff1, WFO1);
    wf_off_build_k<128><<<288, 256, 0, stream>>>(Woff2, WFO2);
    xt_build_k<<<1024, 256, 0, stream>>>(X, XT, XTL);

    // stage 1 (fused offset-conv + deform)
    fused64_k<<<BB * 128 * 4, 512, 0, stream>>>(XT, XTL, WFO1, Boff1, WF1, B1f, Y1);
    bn_stats_part_k<<<512, 256, 0, stream>>>(Y1, PART);
    bn_apply_dual_k<<<1024, 256, 0, stream>>>(Y1, PART, G1, Be1, Y1T, Y1TL);

    // stage 2 (fused offset-conv + deform)
    fused128_k<<<BB * 128 * 4, 512, 0, stream>>>(Y1T, Y1TL, WFO2, Boff2, WF2, B2f, Y2);
    bn_stats_part_k<<<512, 256, 0, stream>>>(Y2, PART);
    bn_apply_out_k<<<(BB * 128 * HWP / 4 + 255) / 256, 256, 0, stream>>>(Y2, PART, G2, Be2, flag, d_out, BB * 128 * HWP / 4);
}

// Round 11
// 295.215 us; speedup vs baseline: 1.0160x; 1.0160x over previous
//
#include <hip/hip_runtime.h>
#include <hip/hip_bf16.h>

#define BB 4
#define H_ 128
#define W_ 128
#define HWP 16384
#define KOFF 18

typedef short short8 __attribute__((ext_vector_type(8)));
typedef float floatx4 __attribute__((ext_vector_type(4)));

// ---- workspace layout (float offsets) ----
#define WS_AB   16
#define WS_CVT  288
#define CVT_TOTAL 4447396
#define WS_WF1  4447744
#define WS_WF2  4484608
#define WS_XT   4558336
#define WS_Y1   7835136
#define WS_Y1T  16223744
#define WS_XTL  18320896         // aliases 2nd half of Y1T; XTL dead before bn_apply_dual writes Y1T
#define WS_WFO1 20418048         // offset-conv wf frags stage1 (hi+lo, 4 ct): 18432 floats
#define WS_WFO2 20436480         // offset-conv wf frags stage2 (hi+lo, 4 ct): 36864 floats
#define WS_PART 21600000
#define WS_Y2   WS_Y1            // Y1 (fp32 NCHW) dead after stage-1 BN-apply; alias
// Y1T_lo lives at WS_CVT (X slot; X fp32 dead after xt_build)
// PARTB1 lives at WS_Y1T (first 524288 floats; Y1T written only later by bn_apply_dual)
// PARTB2 lives at WS_XT  (XT dead after fused64)

// cvt-relative input offsets
#define R_X     0
#define R_WOFF1 4194304
#define R_BOFF1 4204672
#define R_W1    4204690
#define R_B1    4278418
#define R_G1    4278546
#define R_BE1   4278674
#define R_WOFF2 4278802
#define R_BOFF2 4299538
#define R_W2    4299556
#define R_B2    4447012
#define R_G2    4447140
#define R_BE2   4447268

struct SrcPtrs { const void* p[13]; };

__device__ inline short f2bf(float f) {
    __hip_bfloat16 h = __float2bfloat16(f);
    return *reinterpret_cast<short*>(&h);
}
__device__ inline float bf2f(unsigned short u) {
    return __uint_as_float(((unsigned int)u) << 16);
}
__device__ inline float bfu_lo(unsigned int u) { return __uint_as_float(u << 16); }
__device__ inline float bfu_hi(unsigned int u) { return __uint_as_float(u & 0xFFFF0000u); }
__device__ inline float rl_f(float v, int i) {
    return __int_as_float(__builtin_amdgcn_readlane(__float_as_int(v), i));
}

__global__ void probe_dtype_k(const unsigned int* __restrict__ g1, int* __restrict__ flag) {
    if (threadIdx.x == 0 && blockIdx.x == 0) {
        flag[0] = ((g1[0] & 0xFFFFu) != 0u) ? 1 : 0;
    }
}

__global__ __launch_bounds__(256) void convert_inputs_k(SrcPtrs sp, float* __restrict__ dst,
                                                        const int* __restrict__ flag, int total) {
    int i = blockIdx.x * 256 + threadIdx.x;
    if (i >= total) return;
    constexpr int prefix[13] = {0, R_WOFF1, R_BOFF1, R_W1, R_B1, R_G1, R_BE1,
                                R_WOFF2, R_BOFF2, R_W2, R_B2, R_G2, R_BE2};
    const void* src = sp.p[0];
    int base = 0;
#pragma unroll
    for (int q = 1; q < 13; ++q) {
        if (i >= prefix[q]) { src = sp.p[q]; base = prefix[q]; }
    }
    int local = i - base;
    float v;
    if (flag[0] != 0) {
        v = bf2f(((const unsigned short*)src)[local]);
    } else {
        v = ((const float*)src)[local];
    }
    dst[i] = v;
}

// Pack main conv weights into MFMA A-fragment order; frag-k = kk*CIN + ci
template <int CIN>
__global__ __launch_bounds__(256) void wf_build_k(const float* __restrict__ w, short* __restrict__ wf) {
    constexpr int KSTEPS = CIN * 9 / 32;
    int idx = blockIdx.x * 256 + threadIdx.x;
    int j    = idx & 7;
    int lane = (idx >> 3) & 63;
    int rem  = idx >> 9;
    int ks   = rem % KSTEPS;
    int ct   = rem / KSTEPS;
    int co = ct * 16 + (lane & 15);
    int k  = ks * 32 + (lane >> 4) * 8 + j;
    int ci = k & (CIN - 1);
    int kk = k / CIN;
    wf[idx] = f2bf(w[(co * CIN + ci) * 9 + kk]);
}

// Pack offset-conv weights (CO=18 padded to 32), 4 ct-tiles: cc=0,1 hi; cc=2,3 lo residual.
template <int CIN>
__global__ __launch_bounds__(256) void wf_off_build_k(const float* __restrict__ w, short* __restrict__ wf) {
    constexpr int KSTEPS = CIN * 9 / 32;
    int idx = blockIdx.x * 256 + threadIdx.x;   // total 4*KSTEPS*512
    int j    = idx & 7;
    int lane = (idx >> 3) & 63;
    int rem  = idx >> 9;
    int ks   = rem % KSTEPS;
    int cc   = rem / KSTEPS;          // 0..3
    int sel  = cc >> 1;
    int co = (cc & 1) * 16 + (lane & 15);
    int k  = ks * 32 + (lane >> 4) * 8 + j;
    int ci = k & (CIN - 1);
    int kk = k / CIN;
    float v = (co < KOFF) ? w[(co * CIN + ci) * 9 + kk] : 0.f;
    short hi = f2bf(v);
    wf[idx] = sel ? f2bf(v - bf2f((unsigned short)hi)) : hi;
}

// X (fp32 NCHW, C=64) -> XT (bf16 NHWC hi) + XTL (bf16 NHWC lo residual)
__global__ __launch_bounds__(256) void xt_build_k(const float* __restrict__ x,
                                                  unsigned short* __restrict__ xt,
                                                  unsigned short* __restrict__ xtl) {
    __shared__ __align__(4) short s_t[64 * 66];
    __shared__ __align__(4) short s_tl[64 * 66];
    int bi  = blockIdx.x;           // 4 * 256
    int hw0 = (bi & 255) * 64;
    int b   = bi >> 8;
    int t   = threadIdx.x;
    int hwp = t & 63;
#pragma unroll
    for (int it = 0; it < 16; ++it) {
        int c = it * 4 + (t >> 6);
        float v = x[((long)(b * 64 + c) << 14) + hw0 + hwp];
        short hi = f2bf(v);
        s_t[hwp * 66 + c]  = hi;
        s_tl[hwp * 66 + c] = f2bf(v - bf2f((unsigned short)hi));
    }
    __syncthreads();
#pragma unroll
    for (int it = 0; it < 8; ++it) {
        int i  = it * 256 + t;
        int c2 = (i & 31) * 2;
        int hw2 = i >> 5;
        long da = ((long)((b << 14) + hw0 + hw2)) * 64 + c2;
        *(int*)&xt[da]  = *(const int*)&s_t[hw2 * 66 + c2];
        *(int*)&xtl[da] = *(const int*)&s_tl[hw2 * 66 + c2];
    }
}

// ---- im2col table for offset conv (no offsets; tap grid only) ----
__device__ inline int conv_tpk(int h, int w0, int lane, int wv) {
    int tpk = 0;
    if (lane < 36) {
        int r = wv + 8 * lane;
        int p = r & 31;
        int k = r >> 5;
        int y = h - 1 + k / 3;
        int x = w0 + p - 1 + (k % 3);
        int valid = (y >= 0 && y < H_ && x >= 0 && x < W_) ? 1 : 0;
        int yc = min(max(y, 0), H_ - 1), xc = min(max(x, 0), W_ - 1);
        tpk = (yc * W_ + xc) | (valid << 16);
    }
    return tpk;
}

// ---- T14 split conv gathers: load (global->regs, masked) and store (regs->LDS) ----
template <int NJ>
__device__ inline void conv_load64(const unsigned short* __restrict__ xb, unsigned int* ub,
                                   int half, int li, int tpk, int J0) {
#pragma unroll
    for (int j = 0; j < NJ; ++j) {
        int jj = J0 + j;
        int pkA = __builtin_amdgcn_readlane(tpk, 2 * jj);
        int pkB = __builtin_amdgcn_readlane(tpk, 2 * jj + 1);
        int pk = half ? pkB : pkA;
        unsigned int u = *(const unsigned int*)(xb + (pk & 0xFFFF) * 64 + 2 * li);
        ub[j] = (pk >> 16) ? u : 0u;
    }
}
template <int NJ, int PADc>
__device__ inline void conv_store64(short* __restrict__ s_samp, const unsigned int* ub,
                                    int half, int li, int wv, int J0) {
#pragma unroll
    for (int j = 0; j < NJ; ++j) {
        int jj = J0 + j;
        int r = wv + 8 * (half ? (2 * jj + 1) : (2 * jj));
        *(unsigned int*)&s_samp[(r & 31) * PADc + (r >> 5) * 64 + 2 * li] = ub[j];
    }
}
template <int I0, int NJ>
__device__ inline void conv_load128(const unsigned short* __restrict__ xb, unsigned int* ub,
                                    int lane, int tpk) {
#pragma unroll
    for (int j = 0; j < NJ; ++j) {
        int pk = __builtin_amdgcn_readlane(tpk, I0 + j);
        unsigned int u = *(const unsigned int*)(xb + (pk & 0xFFFF) * 128 + 2 * lane);
        ub[j] = (pk >> 16) ? u : 0u;
    }
}
template <int I0, int NJ, int KKB, int PADc>
__device__ inline void conv_store128(short* __restrict__ s_samp, const unsigned int* ub,
                                     int wv, int lane) {
#pragma unroll
    for (int j = 0; j < NJ; ++j) {
        int r = wv + 8 * (I0 + j);
        *(unsigned int*)&s_samp[(r & 31) * PADc + ((r >> 5) - KKB) * 128 + 2 * lane] = ub[j];
    }
}

// ---- deform table build from LDS offsets (lane i owns row r = wv + 8*i, i < 36) ----
__device__ inline void build_table2_lds(const float* __restrict__ s_off,
                                        int h, int w0, int lane, int wv,
                                        int& tpk, float& tw0, float& tw1, float& tw2, float& tw3) {
    tpk = 0; tw0 = tw1 = tw2 = tw3 = 0.f;
    if (lane < 36) {
        int r = wv + 8 * lane;
        int p = r & 31;
        int k = r >> 5;
        int wpix = w0 + p;
        float oy = s_off[(2 * k) * 32 + p];
        float ox = s_off[(2 * k + 1) * 32 + p];
        float py = (float)(h - 1 + (k / 3)) + oy;
        float px = (float)(wpix - 1 + (k % 3)) + ox;
        float fy = floorf(py), fx = floorf(px);
        float wy = py - fy, wx = px - fx;
        int y0 = (int)fy, x0 = (int)fx;
        int y1 = y0 + 1, x1 = x0 + 1;
        bool vy0 = (y0 >= 0) && (y0 < H_);
        bool vy1 = (y1 >= 0) && (y1 < H_);
        bool vx0 = (x0 >= 0) && (x0 < W_);
        bool vx1 = (x1 >= 0) && (x1 < W_);
        float wy0 = 1.f - wy, wx0 = 1.f - wx;
        tw0 = (vy0 && vx0) ? wy0 * wx0 : 0.f;
        tw1 = (vy0 && vx1) ? wy0 * wx  : 0.f;
        tw2 = (vy1 && vx0) ? wy  * wx0 : 0.f;
        tw3 = (vy1 && vx1) ? wy  * wx  : 0.f;
        int iy0 = min(max(y0, 0), H_ - 1), iy1 = min(max(y1, 0), H_ - 1);
        int ix0 = min(max(x0, 0), W_ - 1), ix1 = min(max(x1, 0), W_ - 1);
        int dx = ix1 - ix0;
        int dy = iy1 - iy0;
        tpk = (iy0 * W_ + ix0) | (dx << 14) | (dy << 15);
    }
}

// Batched bilinear gather, CIN=128 (row r = wv + 8*i, pixel = r&31, tap = r>>5)
template <int NB>
__device__ inline void gather_batch128v2(const unsigned short* __restrict__ xb, short* __restrict__ s_samp,
                                         int i0, int kkbase, int wv, int lane,
                                         int tpk, float tw0, float tw1, float tw2, float tw3) {
    constexpr int PADc = 648;
    uint4 ub[NB];
#pragma unroll
    for (int j = 0; j < NB; ++j) {
        int pk = __builtin_amdgcn_readlane(tpk, i0 + j);
        const unsigned short* b00 = xb + (pk & 0x3FFF) * 128;
        const unsigned short* b01 = b00 + ((pk >> 14) & 1) * 128;
        const unsigned short* b10 = b00 + ((pk >> 15) & 1) * (W_ * 128);
        const unsigned short* b11 = b01 + ((pk >> 15) & 1) * (W_ * 128);
        ub[j].x = *(const unsigned int*)(b00 + 2 * lane);
        ub[j].y = *(const unsigned int*)(b01 + 2 * lane);
        ub[j].z = *(const unsigned int*)(b10 + 2 * lane);
        ub[j].w = *(const unsigned int*)(b11 + 2 * lane);
    }
#pragma unroll
    for (int j = 0; j < NB; ++j) {
        int i = i0 + j;
        int r = wv + 8 * i;
        float w00 = rl_f(tw0, i), w01 = rl_f(tw1, i), w10 = rl_f(tw2, i), w11 = rl_f(tw3, i);
        float vlo = w00 * bfu_lo(ub[j].x) + w01 * bfu_lo(ub[j].y)
                  + w10 * bfu_lo(ub[j].z) + w11 * bfu_lo(ub[j].w);
        float vhi = w00 * bfu_hi(ub[j].x) + w01 * bfu_hi(ub[j].y)
                  + w10 * bfu_hi(ub[j].z) + w11 * bfu_hi(ub[j].w);
        __hip_bfloat162 h2 = __float22bfloat162_rn(make_float2(vlo, vhi));
        *(unsigned int*)&s_samp[(r & 31) * PADc + ((r >> 5) - kkbase) * 128 + 2 * lane] =
            *reinterpret_cast<unsigned int*>(&h2);
    }
}

// Batched bilinear gather, CIN=64, dual-row: lanes 0-31 row iA, lanes 32-63 row iB
template <int NBP>
__device__ inline void gather_batch64v2(const unsigned short* __restrict__ xb, short* __restrict__ s_samp,
                                        int i0, int wv, int half, int li,
                                        int tpk, float tw0, float tw1, float tw2, float tw3) {
    constexpr int PADc = 584;
    uint4 ub[NBP];
#pragma unroll
    for (int j = 0; j < NBP; ++j) {
        int iA = i0 + 2 * j, iB = iA + 1;
        int pkA = __builtin_amdgcn_readlane(tpk, iA);
        int pkB = __builtin_amdgcn_readlane(tpk, iB);
        int pk = half ? pkB : pkA;
        const unsigned short* b00 = xb + (pk & 0x3FFF) * 64;
        const unsigned short* b01 = b00 + ((pk >> 14) & 1) * 64;
        const unsigned short* b10 = b00 + ((pk >> 15) & 1) * (W_ * 64);
        const unsigned short* b11 = b01 + ((pk >> 15) & 1) * (W_ * 64);
        ub[j].x = *(const unsigned int*)(b00 + 2 * li);
        ub[j].y = *(const unsigned int*)(b01 + 2 * li);
        ub[j].z = *(const unsigned int*)(b10 + 2 * li);
        ub[j].w = *(const unsigned int*)(b11 + 2 * li);
    }
#pragma unroll
    for (int j = 0; j < NBP; ++j) {
        int iA = i0 + 2 * j, iB = iA + 1;
        float w00 = half ? rl_f(tw0, iB) : rl_f(tw0, iA);
        float w01 = half ? rl_f(tw1, iB) : rl_f(tw1, iA);
        float w10 = half ? rl_f(tw2, iB) : rl_f(tw2, iA);
        float w11 = half ? rl_f(tw3, iB) : rl_f(tw3, iA);
        float vlo = w00 * bfu_lo(ub[j].x) + w01 * bfu_lo(ub[j].y)
                  + w10 * bfu_lo(ub[j].z) + w11 * bfu_lo(ub[j].w);
        float vhi = w00 * bfu_hi(ub[j].x) + w01 * bfu_hi(ub[j].y)
                  + w10 * bfu_hi(ub[j].z) + w11 * bfu_hi(ub[j].w);
        __hip_bfloat162 h2 = __float22bfloat162_rn(make_float2(vlo, vhi));
        int r = wv + 8 * (half ? iB : iA);
        *(unsigned int*)&s_samp[(r & 31) * PADc + (r >> 5) * 64 + 2 * li] =
            *reinterpret_cast<unsigned int*>(&h2);
    }
}

// BN per-block partials epilogue (NON-ATOMIC): 16-lane reduce, write [co][bi] transposed.
__device__ inline void bn_part_epi(floatx4 acc0, floatx4 acc1, int ct, int quad, int p_,
                                   int bi, float* __restrict__ partb) {
#pragma unroll
    for (int r = 0; r < 4; ++r) {
        float sm = acc0[r] + acc1[r];
        float sq = acc0[r] * acc0[r] + acc1[r] * acc1[r];
#pragma unroll
        for (int o = 1; o < 16; o <<= 1) { sm += __shfl_xor(sm, o); sq += __shfl_xor(sq, o); }
        if (p_ == 0) {
            int co = ct * 16 + quad * 4 + r;
            partb[(long)co * 2048 + bi]         = sm;
            partb[(long)(128 + co) * 2048 + bi] = sq;
        }
    }
}

// ===================================================================================
// FUSED stage kernel, CIN=64. v3 wave-roles (ct = wv&1, ksl = wv>>1), dual-ptile conv,
// PADc 584 (all 9 taps resident). LDS: s_samp 36.5K + s_off 2.25K.
// ===================================================================================
__global__ __launch_bounds__(512, 4) void fused64_k(const unsigned short* __restrict__ xt,
                                                    const unsigned short* __restrict__ xtl,
                                                    const short* __restrict__ wfo,
                                                    const float* __restrict__ boff,
                                                    const short* __restrict__ wf,
                                                    const float* __restrict__ bias,
                                                    float* __restrict__ out,
                                                    float* __restrict__ partb) {
    constexpr int KSTEPS = 18;
    constexpr int PADc = 584;
    __shared__ __align__(16) short s_samp[32 * PADc];
    __shared__ float s_off[KOFF * 32];
    float* s_redf = (float*)s_samp;       // scratch, valid only in reduction window

    int bi = blockIdx.x;
    int w0 = (bi & 3) * 32;
    int h  = (bi >> 2) & 127;
    int b  = bi >> 9;
    int t  = threadIdx.x;
    int lane = t & 63;
    int wv   = t >> 6;

    const unsigned short* xbh = xt  + (long)b * HWP * 64;
    const unsigned short* xbl = xtl + (long)b * HWP * 64;
    int half = lane >> 5, li = lane & 31;
    int p_   = lane & 15;
    int quad = lane >> 4;

    // ---------------- offset conv phase (split-bf16, dual-ptile, ksl4) ----------------
    {
        int tpkc = conv_tpk(h, w0, lane, wv);
        int ct  = wv & 1;
        int ksl = wv >> 1;          // 0..3
        floatx4 acc0, acc1;
#pragma unroll
        for (int r = 0; r < 4; ++r) {
            int co = ct * 16 + quad * 4 + r;
            float bv = (ksl == 0 && co < KOFF) ? boff[co] : 0.f;
            acc0[r] = bv;
            acc1[r] = bv;
        }

        // stage A-hi (taps 0-7, ks 0..15)
        {
            unsigned int ubA[16];
            conv_load64<16>(xbh, ubA, half, li, tpkc, 0);
            conv_store64<16, PADc>(s_samp, ubA, half, li, wv, 0);
        }
        __syncthreads();
        unsigned int ubC[2];
        conv_load64<2>(xbh, ubC, half, li, tpkc, 16);     // C-hi loads hidden under A-hi MFMAs
#pragma unroll
        for (int ki = 0; ki < 4; ++ki) {
            int ks = ksl * 4 + ki;
            short8 b0 = *(const short8*)&s_samp[p_ * PADc + ks * 32 + quad * 8];
            short8 b1 = *(const short8*)&s_samp[(16 + p_) * PADc + ks * 32 + quad * 8];
            short8 ah = *(const short8*)&wfo[(((long)ct * KSTEPS + ks) * 64 + lane) * 8];
            short8 al = *(const short8*)&wfo[(((long)(2 + ct) * KSTEPS + ks) * 64 + lane) * 8];
            acc0 = __builtin_amdgcn_mfma_f32_16x16x32_bf16(ah, b0, acc0, 0, 0, 0);
            acc0 = __builtin_amdgcn_mfma_f32_16x16x32_bf16(al, b0, acc0, 0, 0, 0);
            acc1 = __builtin_amdgcn_mfma_f32_16x16x32_bf16(ah, b1, acc1, 0, 0, 0);
            acc1 = __builtin_amdgcn_mfma_f32_16x16x32_bf16(al, b1, acc1, 0, 0, 0);
        }
        __syncthreads();
        conv_store64<2, PADc>(s_samp, ubC, half, li, wv, 16);
        __syncthreads();
        unsigned int ubA2[16];
        conv_load64<16>(xbl, ubA2, half, li, tpkc, 0);    // A-lo loads hidden under C-hi MFMAs
        if (ksl < 2) {
            int ks = 16 + ksl;
            short8 b0 = *(const short8*)&s_samp[p_ * PADc + ks * 32 + quad * 8];
            short8 b1 = *(const short8*)&s_samp[(16 + p_) * PADc + ks * 32 + quad * 8];
            short8 ah = *(const short8*)&wfo[(((long)ct * KSTEPS + ks) * 64 + lane) * 8];
            short8 al = *(const short8*)&wfo[(((long)(2 + ct) * KSTEPS + ks) * 64 + lane) * 8];
            acc0 = __builtin_amdgcn_mfma_f32_16x16x32_bf16(ah, b0, acc0, 0, 0, 0);
            acc0 = __builtin_amdgcn_mfma_f32_16x16x32_bf16(al, b0, acc0, 0, 0, 0);
            acc1 = __builtin_amdgcn_mfma_f32_16x16x32_bf16(ah, b1, acc1, 0, 0, 0);
            acc1 = __builtin_amdgcn_mfma_f32_16x16x32_bf16(al, b1, acc1, 0, 0, 0);
        }
        __syncthreads();
        conv_store64<16, PADc>(s_samp, ubA2, half, li, wv, 0);
        __syncthreads();
        conv_load64<2>(xbl, ubC, half, li, tpkc, 16);     // C-lo loads hidden under A-lo MFMAs
#pragma unroll
        for (int ki = 0; ki < 4; ++ki) {
            int ks = ksl * 4 + ki;
            short8 b0 = *(const short8*)&s_samp[p_ * PADc + ks * 32 + quad * 8];
            short8 b1 = *(const short8*)&s_samp[(16 + p_) * PADc + ks * 32 + quad * 8];
            short8 ah = *(const short8*)&wfo[(((long)ct * KSTEPS + ks) * 64 + lane) * 8];
            acc0 = __builtin_amdgcn_mfma_f32_16x16x32_bf16(ah, b0, acc0, 0, 0, 0);
            acc1 = __builtin_amdgcn_mfma_f32_16x16x32_bf16(ah, b1, acc1, 0, 0, 0);
        }
        __syncthreads();
        conv_store64<2, PADc>(s_samp, ubC, half, li, wv, 16);
        __syncthreads();
        if (ksl < 2) {
            int ks = 16 + ksl;
            short8 b0 = *(const short8*)&s_samp[p_ * PADc + ks * 32 + quad * 8];
            short8 b1 = *(const short8*)&s_samp[(16 + p_) * PADc + ks * 32 + quad * 8];
            short8 ah = *(const short8*)&wfo[(((long)ct * KSTEPS + ks) * 64 + lane) * 8];
            acc0 = __builtin_amdgcn_mfma_f32_16x16x32_bf16(ah, b0, acc0, 0, 0, 0);
            acc1 = __builtin_amdgcn_mfma_f32_16x16x32_bf16(ah, b1, acc1, 0, 0, 0);
        }

        // K-reduction through s_samp scratch
        __syncthreads();
        if (ksl != 0) {
#pragma unroll
            for (int r = 0; r < 4; ++r) {
                s_redf[(((ksl - 1) * 4 + ct * 2 + 0) * 256) + (quad * 4 + r) * 16 + p_] = acc0[r];
                s_redf[(((ksl - 1) * 4 + ct * 2 + 1) * 256) + (quad * 4 + r) * 16 + p_] = acc1[r];
            }
        }
        __syncthreads();
        if (ksl == 0) {
#pragma unroll
            for (int r = 0; r < 4; ++r) {
                int co = ct * 16 + quad * 4 + r;
                if (co < KOFF) {
                    float v0 = acc0[r], v1 = acc1[r];
#pragma unroll
                    for (int s = 1; s < 4; ++s) {
                        v0 += s_redf[(((s - 1) * 4 + ct * 2 + 0) * 256) + (quad * 4 + r) * 16 + p_];
                        v1 += s_redf[(((s - 1) * 4 + ct * 2 + 1) * 256) + (quad * 4 + r) * 16 + p_];
                    }
                    s_off[co * 32 + p_]      = v0;
                    s_off[co * 32 + 16 + p_] = v1;
                }
            }
        }
        __syncthreads();
    }

    // ---------------- deform conv phase ----------------
    int tpk; float tw0, tw1, tw2, tw3;
    build_table2_lds(s_off, h, w0, lane, wv, tpk, tw0, tw1, tw2, tw3);

    gather_batch64v2<6>(xbh, s_samp,  0, wv, half, li, tpk, tw0, tw1, tw2, tw3);
    gather_batch64v2<6>(xbh, s_samp, 12, wv, half, li, tpk, tw0, tw1, tw2, tw3);
    gather_batch64v2<6>(xbh, s_samp, 24, wv, half, li, tpk, tw0, tw1, tw2, tw3);
    __syncthreads();

    int ct = wv;
    floatx4 acc0, acc1;
#pragma unroll
    for (int r = 0; r < 4; ++r) {
        float bv = bias[ct * 16 + quad * 4 + r];
        acc0[r] = bv;
        acc1[r] = bv;
    }
#pragma unroll 3
    for (int ks = 0; ks < KSTEPS; ++ks) {
        short8 a  = *(const short8*)&wf[(((long)ct * KSTEPS + ks) * 64 + lane) * 8];
        short8 b0 = *(const short8*)&s_samp[p_ * PADc + ks * 32 + quad * 8];
        short8 b1 = *(const short8*)&s_samp[(16 + p_) * PADc + ks * 32 + quad * 8];
        acc0 = __builtin_amdgcn_mfma_f32_16x16x32_bf16(a, b0, acc0, 0, 0, 0);
        acc1 = __builtin_amdgcn_mfma_f32_16x16x32_bf16(a, b1, acc1, 0, 0, 0);
    }

    long ob = ((long)(b * 128) << 14) + (h << 7) + w0 + p_;
#pragma unroll
    for (int r = 0; r < 4; ++r) {
        long cpl = (long)(ct * 16 + quad * 4 + r) << 14;
        out[ob + cpl]      = acc0[r];
        out[ob + 16 + cpl] = acc1[r];
    }
    bn_part_epi(acc0, acc1, ct, quad, p_, bi, partb);
}

// ===================================================================================
// FUSED stage kernel, CIN=128. v3 wave-roles, dual-ptile conv, PADc 648.
// LDS: s_samp 41.5K + s_off 2.25K.
// ===================================================================================
__global__ __launch_bounds__(512, 4) void fused128_k(const unsigned short* __restrict__ xt,
                                                     const unsigned short* __restrict__ xtl,
                                                     const short* __restrict__ wfo,
                                                     const float* __restrict__ boff,
                                                     const short* __restrict__ wf,
                                                     const float* __restrict__ bias,
                                                     float* __restrict__ out,
                                                     float* __restrict__ partb) {
    constexpr int KSTEPS = 36;
    constexpr int PADc = 648;
    __shared__ __align__(16) short s_samp[32 * PADc];
    __shared__ float s_off[KOFF * 32];
    float* s_redf = (float*)s_samp;

    int bi = blockIdx.x;
    int w0 = (bi & 3) * 32;
    int h  = (bi >> 2) & 127;
    int b  = bi >> 9;
    int t  = threadIdx.x;
    int lane = t & 63;
    int wv   = t >> 6;

    const unsigned short* xbh = xt  + (long)b * HWP * 128;
    const unsigned short* xbl = xtl + (long)b * HWP * 128;
    int p_   = lane & 15;
    int quad = lane >> 4;

    // ---------------- offset conv phase (split-bf16, dual-ptile, ksl4) ----------------
    {
        int tpkc = conv_tpk(h, w0, lane, wv);
        int ct  = wv & 1;
        int ksl = wv >> 1;          // 0..3
        floatx4 acc0, acc1;
#pragma unroll
        for (int r = 0; r < 4; ++r) {
            int co = ct * 16 + quad * 4 + r;
            float bv = (ksl == 0 && co < KOFF) ? boff[co] : 0.f;
            acc0[r] = bv;
            acc1[r] = bv;
        }

        unsigned int ubA[16], ubB[20];
        // stage A-hi (taps 0..3, ks 0..15)
        conv_load128<0, 16>(xbh, ubA, lane, tpkc);
        conv_store128<0, 16, 0, PADc>(s_samp, ubA, wv, lane);
        __syncthreads();
        conv_load128<16, 20>(xbh, ubB, lane, tpkc);   // B-hi loads hidden under A-hi MFMAs
#pragma unroll
        for (int ki = 0; ki < 4; ++ki) {
            int ks = ksl * 4 + ki;
            short8 b0 = *(const short8*)&s_samp[p_ * PADc + ks * 32 + quad * 8];
            short8 b1 = *(const short8*)&s_samp[(16 + p_) * PADc + ks * 32 + quad * 8];
            short8 ah = *(const short8*)&wfo[(((long)ct * KSTEPS + ks) * 64 + lane) * 8];
            short8 al = *(const short8*)&wfo[(((long)(2 + ct) * KSTEPS + ks) * 64 + lane) * 8];
            acc0 = __builtin_amdgcn_mfma_f32_16x16x32_bf16(ah, b0, acc0, 0, 0, 0);
            acc0 = __builtin_amdgcn_mfma_f32_16x16x32_bf16(al, b0, acc0, 0, 0, 0);
            acc1 = __builtin_amdgcn_mfma_f32_16x16x32_bf16(ah, b1, acc1, 0, 0, 0);
            acc1 = __builtin_amdgcn_mfma_f32_16x16x32_bf16(al, b1, acc1, 0, 0, 0);
        }
        __syncthreads();
        conv_store128<16, 20, 4, PADc>(s_samp, ubB, wv, lane);
        __syncthreads();
        conv_load128<0, 16>(xbl, ubA, lane, tpkc);    // A-lo loads hidden under B-hi MFMAs
#pragma unroll
        for (int ki = 0; ki < 5; ++ki) {
            int ks = 16 + ksl * 5 + ki;
            short8 b0 = *(const short8*)&s_samp[p_ * PADc + (ks - 16) * 32 + quad * 8];
            short8 b1 = *(const short8*)&s_samp[(16 + p_) * PADc + (ks - 16) * 32 + quad * 8];
            short8 ah = *(const short8*)&wfo[(((long)ct * KSTEPS + ks) * 64 + lane) * 8];
            short8 al = *(const short8*)&wfo[(((long)(2 + ct) * KSTEPS + ks) * 64 + lane) * 8];
            acc0 = __builtin_amdgcn_mfma_f32_16x16x32_bf16(ah, b0, acc0, 0, 0, 0);
            acc0 = __builtin_amdgcn_mfma_f32_16x16x32_bf16(al, b0, acc0, 0, 0, 0);
            acc1 = __builtin_amdgcn_mfma_f32_16x16x32_bf16(ah, b1, acc1, 0, 0, 0);
            acc1 = __builtin_amdgcn_mfma_f32_16x16x32_bf16(al, b1, acc1, 0, 0, 0);
        }
        __syncthreads();
        conv_store128<0, 16, 0, PADc>(s_samp, ubA, wv, lane);
        __syncthreads();
        conv_load128<16, 20>(xbl, ubB, lane, tpkc);   // B-lo loads hidden under A-lo MFMAs
#pragma unroll
        for (int ki = 0; ki < 4; ++ki) {
            int ks = ksl * 4 + ki;
            short8 b0 = *(const short8*)&s_samp[p_ * PADc + ks * 32 + quad * 8];
            short8 b1 = *(const short8*)&s_samp[(16 + p_) * PADc + ks * 32 + quad * 8];
            short8 ah = *(const short8*)&wfo[(((long)ct * KSTEPS + ks) * 64 + lane) * 8];
            acc0 = __builtin_amdgcn_mfma_f32_16x16x32_bf16(ah, b0, acc0, 0, 0, 0);
            acc1 = __builtin_amdgcn_mfma_f32_16x16x32_bf16(ah, b1, acc1, 0, 0, 0);
        }
        __syncthreads();
        conv_store128<16, 20, 4, PADc>(s_samp, ubB, wv, lane);
        __syncthreads();
#pragma unroll
        for (int ki = 0; ki < 5; ++ki) {
            int ks = 16 + ksl * 5 + ki;
            short8 b0 = *(const short8*)&s_samp[p_ * PADc + (ks - 16) * 32 + quad * 8];
            short8 b1 = *(const short8*)&s_samp[(16 + p_) * PADc + (ks - 16) * 32 + quad * 8];
            short8 ah = *(const short8*)&wfo[(((long)ct * KSTEPS + ks) * 64 + lane) * 8];
            acc0 = __builtin_amdgcn_mfma_f32_16x16x32_bf16(ah, b0, acc0, 0, 0, 0);
            acc1 = __builtin_amdgcn_mfma_f32_16x16x32_bf16(ah, b1, acc1, 0, 0, 0);
        }

        // K-reduction through s_samp scratch
        __syncthreads();
        if (ksl != 0) {
#pragma unroll
            for (int r = 0; r < 4; ++r) {
                s_redf[(((ksl - 1) * 4 + ct * 2 + 0) * 256) + (quad * 4 + r) * 16 + p_] = acc0[r];
                s_redf[(((ksl - 1) * 4 + ct * 2 + 1) * 256) + (quad * 4 + r) * 16 + p_] = acc1[r];
            }
        }
        __syncthreads();
        if (ksl == 0) {
#pragma unroll
            for (int r = 0; r < 4; ++r) {
                int co = ct * 16 + quad * 4 + r;
                if (co < KOFF) {
                    float v0 = acc0[r], v1 = acc1[r];
#pragma unroll
                    for (int s = 1; s < 4; ++s) {
                        v0 += s_redf[(((s - 1) * 4 + ct * 2 + 0) * 256) + (quad * 4 + r) * 16 + p_];
                        v1 += s_redf[(((s - 1) * 4 + ct * 2 + 1) * 256) + (quad * 4 + r) * 16 + p_];
                    }
                    s_off[co * 32 + p_]      = v0;
                    s_off[co * 32 + 16 + p_] = v1;
                }
            }
        }
        __syncthreads();
    }

    // ---------------- deform conv phase ----------------
    int tpk; float tw0, tw1, tw2, tw3;
    build_table2_lds(s_off, h, w0, lane, wv, tpk, tw0, tw1, tw2, tw3);

    int ct = wv;
    floatx4 acc0, acc1;
#pragma unroll
    for (int r = 0; r < 4; ++r) {
        float bv = bias[ct * 16 + quad * 4 + r];
        acc0[r] = bv;
        acc1[r] = bv;
    }

    gather_batch128v2<8>(xbh, s_samp, 0, 0, wv, lane, tpk, tw0, tw1, tw2, tw3);
    gather_batch128v2<8>(xbh, s_samp, 8, 0, wv, lane, tpk, tw0, tw1, tw2, tw3);
    __syncthreads();
#pragma unroll 4
    for (int ks = 0; ks < 16; ++ks) {
        short8 a  = *(const short8*)&wf[(((long)ct * KSTEPS + ks) * 64 + lane) * 8];
        short8 b0 = *(const short8*)&s_samp[p_ * PADc + ks * 32 + quad * 8];
        short8 b1 = *(const short8*)&s_samp[(16 + p_) * PADc + ks * 32 + quad * 8];
        acc0 = __builtin_amdgcn_mfma_f32_16x16x32_bf16(a, b0, acc0, 0, 0, 0);
        acc1 = __builtin_amdgcn_mfma_f32_16x16x32_bf16(a, b1, acc1, 0, 0, 0);
    }
    __syncthreads();

    gather_batch128v2<5>(xbh, s_samp, 16, 4, wv, lane, tpk, tw0, tw1, tw2, tw3);
    gather_batch128v2<5>(xbh, s_samp, 21, 4, wv, lane, tpk, tw0, tw1, tw2, tw3);
    gather_batch128v2<5>(xbh, s_samp, 26, 4, wv, lane, tpk, tw0, tw1, tw2, tw3);
    gather_batch128v2<5>(xbh, s_samp, 31, 4, wv, lane, tpk, tw0, tw1, tw2, tw3);
    __syncthreads();
#pragma unroll 4
    for (int ks = 16; ks < KSTEPS; ++ks) {
        short8 a  = *(const short8*)&wf[(((long)ct * KSTEPS + ks) * 64 + lane) * 8];
        short8 b0 = *(const short8*)&s_samp[p_ * PADc + (ks - 16) * 32 + quad * 8];
        short8 b1 = *(const short8*)&s_samp[(16 + p_) * PADc + (ks - 16) * 32 + quad * 8];
        acc0 = __builtin_amdgcn_mfma_f32_16x16x32_bf16(a, b0, acc0, 0, 0, 0);
        acc1 = __builtin_amdgcn_mfma_f32_16x16x32_bf16(a, b1, acc1, 0, 0, 0);
    }

    long ob = ((long)(b * 128) << 14) + (h << 7) + w0 + p_;
#pragma unroll
    for (int r = 0; r < 4; ++r) {
        long cpl = (long)(ct * 16 + quad * 4 + r) << 14;
        out[ob + cpl]      = acc0[r];
        out[ob + 16 + cpl] = acc1[r];
    }
    bn_part_epi(acc0, acc1, ct, quad, p_, bi, partb);
}

// Reduce per-block BN partials [co][2048] -> part[c], part[128+c]
__global__ __launch_bounds__(256) void bn_reduce_k(const float* __restrict__ pb, float* __restrict__ part) {
    int c = blockIdx.x;           // 0..127
    int t = threadIdx.x;
    float sm = 0.f, sq = 0.f;
#pragma unroll
    for (int i = 0; i < 8; ++i) {
        sm += pb[(long)c * 2048 + i * 256 + t];
        sq += pb[(long)(128 + c) * 2048 + i * 256 + t];
    }
#pragma unroll
    for (int o = 32; o > 0; o >>= 1) { sm += __shfl_down(sm, o); sq += __shfl_down(sq, o); }
    __shared__ float s1[4], s2[4];
    int wave = t >> 6;
    if ((t & 63) == 0) { s1[wave] = sm; s2[wave] = sq; }
    __syncthreads();
    if (t == 0) {
        part[c]       = s1[0] + s1[1] + s1[2] + s1[3];
        part[128 + c] = s2[0] + s2[1] + s2[2] + s2[3];
    }
}

// BN+ReLU: read raw fp32 NCHW, write transposed bf16 NHWC hi + lo copies (no fp32 writeback).
__global__ __launch_bounds__(256) void bn_apply_dual_k(const float* __restrict__ y, const float* __restrict__ part,
                                                       const float* __restrict__ g, const float* __restrict__ be,
                                                       unsigned short* __restrict__ yt,
                                                       unsigned short* __restrict__ ytl) {
    __shared__ __align__(4) short s_t[64 * 134];
    __shared__ __align__(4) short s_tl[64 * 134];
    __shared__ float s_a[128], s_sh[128];
    int t = threadIdx.x;
    if (t < 128) {
        float sum = part[t];
        float ss  = part[128 + t];
        float mean = sum * (1.f / 65536.f);
        float var  = ss  * (1.f / 65536.f) - mean * mean;
        float inv  = rsqrtf(var + 1e-5f);
        float a = g[t] * inv;
        s_a[t]  = a;
        s_sh[t] = be[t] - mean * a;
    }
    __syncthreads();

    int bi  = blockIdx.x;          // 4 * 256
    int hw0 = (bi & 255) * 64;
    int b   = bi >> 8;
    int hwp = t & 63;
#pragma unroll 4
    for (int it = 0; it < 32; ++it) {
        int c = it * 4 + (t >> 6);
        float a = s_a[c], sh = s_sh[c];
        long addr = ((long)(b * 128 + c) << 14) + hw0 + hwp;
        float v = y[addr];
        v = fmaxf(v * a + sh, 0.f);
        short hi = f2bf(v);
        s_t[hwp * 134 + c]  = hi;
        s_tl[hwp * 134 + c] = f2bf(v - bf2f((unsigned short)hi));
    }
    __syncthreads();
#pragma unroll 4
    for (int it = 0; it < 16; ++it) {
        int i   = it * 256 + t;
        int c2  = (i & 63) * 2;
        int hw2 = i >> 6;
        long da = ((long)((b << 14) + hw0 + hw2)) * 128 + c2;
        *(int*)&yt[da]  = *(const int*)&s_t[hw2 * 134 + c2];
        *(int*)&ytl[da] = *(const int*)&s_tl[hw2 * 134 + c2];
    }
}

// Final BN+ReLU -> d_out (fp32 or bf16 per flag).
__global__ __launch_bounds__(256) void bn_apply_out_k(const float* __restrict__ y, const float* __restrict__ part,
                                                      const float* __restrict__ g, const float* __restrict__ be,
                                                      const int* __restrict__ flag, void* __restrict__ out, int total4) {
    __shared__ float s_a[128], s_sh[128];
    int t = threadIdx.x;
    if (t < 128) {
        float sum = part[t];
        float ss  = part[128 + t];
        float mean = sum * (1.f / 65536.f);
        float var  = ss  * (1.f / 65536.f) - mean * mean;
        float inv  = rsqrtf(var + 1e-5f);
        float a = g[t] * inv;
        s_a[t]  = a;
        s_sh[t] = be[t] - mean * a;
    }
    __syncthreads();

    int i = blockIdx.x * 256 + t;
    if (i >= total4) return;
    int c = (i >> 12) & 127;
    float a = s_a[c], sh = s_sh[c];
    float4 v = reinterpret_cast<const float4*>(y)[i];
    v.x = fmaxf(v.x * a + sh, 0.f);
    v.y = fmaxf(v.y * a + sh, 0.f);
    v.z = fmaxf(v.z * a + sh, 0.f);
    v.w = fmaxf(v.w * a + sh, 0.f);
    if (flag[0] != 0) {
        ushort4 u;
        u.x = (unsigned short)f2bf(v.x);
        u.y = (unsigned short)f2bf(v.y);
        u.z = (unsigned short)f2bf(v.z);
        u.w = (unsigned short)f2bf(v.w);
        reinterpret_cast<ushort4*>(out)[i] = u;
    } else {
        reinterpret_cast<float4*>(out)[i] = v;
    }
}

extern "C" void kernel_launch(void* const* d_in, const int* in_sizes, int n_in,
                              void* d_out, int out_size, void* d_ws, size_t ws_size,
                              hipStream_t stream) {
    float* ws   = (float*)d_ws;
    int*   flag = (int*)d_ws;
    float* cvt  = ws + WS_CVT;

    const float* X     = cvt + R_X;
    const float* Woff1 = cvt + R_WOFF1;
    const float* Boff1 = cvt + R_BOFF1;
    const float* W1f   = cvt + R_W1;
    const float* B1f   = cvt + R_B1;
    const float* G1    = cvt + R_G1;
    const float* Be1   = cvt + R_BE1;
    const float* Woff2 = cvt + R_WOFF2;
    const float* Boff2 = cvt + R_BOFF2;
    const float* W2f   = cvt + R_W2;
    const float* B2f   = cvt + R_B2;
    const float* G2    = cvt + R_G2;
    const float* Be2   = cvt + R_BE2;

    short* WF1  = (short*)(ws + WS_WF1);
    short* WF2  = (short*)(ws + WS_WF2);
    short* WFO1 = (short*)(ws + WS_WFO1);
    short* WFO2 = (short*)(ws + WS_WFO2);
    unsigned short* XT   = (unsigned short*)(ws + WS_XT);
    unsigned short* XTL  = (unsigned short*)(ws + WS_XTL);
    unsigned short* Y1T  = (unsigned short*)(ws + WS_Y1T);
    unsigned short* Y1TL = (unsigned short*)(ws + WS_CVT);   // X slot; X fp32 dead after xt_build
    float* PART   = ws + WS_PART;
    float* PARTB1 = ws + WS_Y1T;    // first 524288 floats of Y1T slot (Y1T written later)
    float* PARTB2 = ws + WS_XT;     // XT slot, dead after fused64
    float* Y1   = ws + WS_Y1;
    float* Y2   = ws + WS_Y2;

    SrcPtrs sp;
    for (int j = 0; j < 13; ++j) sp.p[j] = d_in[j];

    probe_dtype_k<<<1, 64, 0, stream>>>((const unsigned int*)d_in[5], flag);
    convert_inputs_k<<<(CVT_TOTAL + 255) / 256, 256, 0, stream>>>(sp, cvt, flag, CVT_TOTAL);
    wf_build_k<64><<<288, 256, 0, stream>>>(W1f, WF1);
    wf_build_k<128><<<576, 256, 0, stream>>>(W2f, WF2);
    wf_off_build_k<64><<<144, 256, 0, stream>>>(Woff1, WFO1);
    wf_off_build_k<128><<<288, 256, 0, stream>>>(Woff2, WFO2);
    xt_build_k<<<1024, 256, 0, stream>>>(X, XT, XTL);

    // stage 1 (fused offset-conv + deform + BN partials)
    fused64_k<<<BB * 128 * 4, 512, 0, stream>>>(XT, XTL, WFO1, Boff1, WF1, B1f, Y1, PARTB1);
    bn_reduce_k<<<128, 256, 0, stream>>>(PARTB1, PART);
    bn_apply_dual_k<<<1024, 256, 0, stream>>>(Y1, PART, G1, Be1, Y1T, Y1TL);

    // stage 2 (fused offset-conv + deform + BN partials)
    fused128_k<<<BB * 128 * 4, 512, 0, stream>>>(Y1T, Y1TL, WFO2, Boff2, WF2, B2f, Y2, PARTB2);
    bn_reduce_k<<<128, 256, 0, stream>>>(PARTB2, PART);
    bn_apply_out_k<<<(BB * 128 * HWP / 4 + 255) / 256, 256, 0, stream>>>(Y2, PART, G2, Be2, flag, d_out, BB * 128 * HWP / 4);
}